// Round 1
// 465.694 us; speedup vs baseline: 1.6169x; 1.6169x over previous
//
#include <hip/hip_runtime.h>

static constexpr int kBN   = 737280;   // B*T*V*H*W
static constexpr int kSlab = 92160;    // V*H*W
static constexpr int kNT   = 512;      // NUM_TRACKS
static constexpr int kNSeg = 4096;     // (B*T)*NUM_TRACKS
static constexpr int kChunk = 5120;    // elements per count/fill block (18 per slab, single bt)

// ---------------- count (LDS-privatized histogram) ----------------
__global__ __launch_bounds__(1024) void k_count(const int* __restrict__ gid, int* cnt) {
    __shared__ int h[kNT];
    int tid = threadIdx.x;
    if (tid < kNT) h[tid] = 0;
    __syncthreads();
    int chunk0 = blockIdx.x * kChunk;
    int bt = chunk0 / kSlab;            // chunk never straddles a slab (92160 = 18*5120)
    for (int j = tid; j < kChunk; j += 1024) {
        int id = gid[chunk0 + j];
        if (id >= 0) atomicAdd(&h[id], 1);
    }
    __syncthreads();
    if (tid < kNT) { int v = h[tid]; if (v) atomicAdd(&cnt[bt * kNT + tid], v); }
}

// ---------------- exclusive scan of 4096 counts (single block) ----------------
__global__ __launch_bounds__(1024) void k_scan(const int* __restrict__ cnt, int* offs, int* cursor) {
    __shared__ int part[1024];
    int tid = threadIdx.x;
    int b = tid * 4;
    int v0 = cnt[b], v1 = cnt[b + 1], v2 = cnt[b + 2], v3 = cnt[b + 3];
    int s01 = v0 + v1, s = s01 + v2 + v3;
    part[tid] = s;
    __syncthreads();
    for (int off = 1; off < 1024; off <<= 1) {
        int t = (tid >= off) ? part[tid - off] : 0;
        __syncthreads();
        part[tid] += t;
        __syncthreads();
    }
    int base = part[tid] - s;           // exclusive prefix of this thread's group of 4
    int o0 = base, o1 = base + v0, o2 = base + s01, o3 = base + s01 + v2;
    offs[b] = o0; offs[b + 1] = o1; offs[b + 2] = o2; offs[b + 3] = o3;
    cursor[b] = o0; cursor[b + 1] = o1; cursor[b + 2] = o2; cursor[b + 3] = o3;
}

// ---------------- fill per-segment index lists (privatized) ----------------
__global__ __launch_bounds__(1024) void k_fill(const int* __restrict__ gid, int* cursor, int* lists) {
    __shared__ int lcnt[kNT];
    __shared__ int lbase[kNT];
    int tid = threadIdx.x;
    if (tid < kNT) lcnt[tid] = 0;
    __syncthreads();
    int chunk0 = blockIdx.x * kChunk;
    int bt = chunk0 / kSlab;
    int rank[5], ids[5];
#pragma unroll
    for (int u = 0; u < 5; u++) {
        int id = gid[chunk0 + tid + u * 1024];
        ids[u] = id;
        rank[u] = (id >= 0) ? atomicAdd(&lcnt[id], 1) : 0;
    }
    __syncthreads();
    if (tid < kNT) { int c = lcnt[tid]; lbase[tid] = c ? atomicAdd(&cursor[bt * kNT + tid], c) : 0; }
    __syncthreads();
#pragma unroll
    for (int u = 0; u < 5; u++) {
        int id = ids[u];
        if (id >= 0) lists[lbase[id] + rank[u]] = chunk0 + tid + u * 1024;
    }
}

// ---------------- per-wave channel reduce helper ----------------
template<int CNT>
__device__ __forceinline__ void wreduce_store(float (&a)[17], int lane, int tb, float* totl) {
#pragma unroll
    for (int c = 0; c < CNT; c++) {
        float v = a[c];
#pragma unroll
        for (int m = 1; m < 64; m <<= 1) v += __shfl_xor(v, m, 64);
        if (lane == 0) totl[tb + c] = v;
    }
}

// ---------------- per-segment merge: one block per segment ----------------
// Waves split the 66 accumulation channels: w0=cen/off/opac/scale/rot/fd (17),
// w1=inst[0:16], w2=inst[16:32], w3=motion(16)+z2. Register accumulate + shfl
// reduce -- no LDS atomics. z1/c-sum reduction keeps the EXACT add order of the
// previous passing kernel (mc1 bit-identical -> active set unchanged).
__global__ __launch_bounds__(256, 4) void k_seg(
        const int* __restrict__ lists, const int* __restrict__ offs, const int* __restrict__ cnt,
        const float* __restrict__ keep, const float* __restrict__ center,
        const float* __restrict__ offsetp, const float* __restrict__ opacity,
        const float* __restrict__ scale, const float* __restrict__ rot,
        const float* __restrict__ fd, const float* __restrict__ inst,
        const float* __restrict__ motion,
        float* __restrict__ mc1g, int* __restrict__ repg,
        float* __restrict__ merged) {
    // XCD-chunked swizzle: 8 XCDs, 512 segments (one bt-slab) per XCD ->
    // keep+center slab (~1.4 MB) stays L2-resident per XCD.
    int s = ((blockIdx.x & 7) << 9) | (blockIdx.x >> 3);
    int n = cnt[s];
    if (n < 2) return;                  // not dup: untouched, k_out passes through
    int base = offs[s];
    int tid = threadIdx.x;
    int lane = tid & 63;
    int wv = tid >> 6;

    __shared__ int   idxs[256];
    __shared__ float kk[256];
    __shared__ float c0s[256], c1s[256], c2s[256];
    __shared__ float e2s[256];
    __shared__ float red4[256][5];      // pad 5 -> conflict-free tree
    __shared__ float wm1[4], wm2[4];
    __shared__ int   wri[4];
    __shared__ float totl[66];

    // ---- pass 1: stage keep/center/idx + m1 (max, order-free) ----
    float lmax = -1e30f;
    for (int j = tid; j < n; j += 256) {
        int i = lists[base + j];
        float k = keep[i];
        float cx = center[3 * i + 0], cy = center[3 * i + 1], cz = center[3 * i + 2];
        if (j < 256) { idxs[j] = i; kk[j] = k; c0s[j] = cx; c1s[j] = cy; c2s[j] = cz; }
        lmax = fmaxf(lmax, k);
    }
#pragma unroll
    for (int m = 1; m < 64; m <<= 1) lmax = fmaxf(lmax, __shfl_xor(lmax, m, 64));
    if (lane == 0) wm1[wv] = lmax;
    __syncthreads();
    float m1 = fmaxf(fmaxf(wm1[0], wm1[1]), fmaxf(wm1[2], wm1[3]));

    // ---- pass 2: z1 + weighted center sums (order-exact vs previous kernel) ----
    float lz = 0.f, l0 = 0.f, l1 = 0.f, l2 = 0.f;
    for (int j = tid; j < n; j += 256) {
        float k, cx, cy, cz;
        if (j < 256) { k = kk[j]; cx = c0s[j]; cy = c1s[j]; cz = c2s[j]; }
        else { int i = lists[base + j]; k = keep[i];
               cx = center[3 * i + 0]; cy = center[3 * i + 1]; cz = center[3 * i + 2]; }
        float e = expf(k - m1);
        lz += e; l0 += e * cx; l1 += e * cy; l2 += e * cz;
    }
    red4[tid][0] = lz; red4[tid][1] = l0; red4[tid][2] = l1; red4[tid][3] = l2;
    __syncthreads();
    for (int o = 128; o; o >>= 1) {
        if (tid < o) {
            red4[tid][0] += red4[tid + o][0]; red4[tid][1] += red4[tid + o][1];
            red4[tid][2] += red4[tid + o][2]; red4[tid][3] += red4[tid + o][3];
        }
        __syncthreads();
    }
    float z1 = red4[0][0];
    float inv1 = 1.0f / fmaxf(z1, 1e-20f);
    float mc0 = red4[0][1] * inv1, mcy = red4[0][2] * inv1, mcz = red4[0][3] * inv1;

    // ---- pass 3: m2 over active (max, order-free); cache act flag ----
    float lm2 = -1e30f;
    for (int j = tid; j < n; j += 256) {
        float k, cx, cy, cz;
        if (j < 256) { k = kk[j]; cx = c0s[j]; cy = c1s[j]; cz = c2s[j]; }
        else { int i = lists[base + j]; k = keep[i];
               cx = center[3 * i + 0]; cy = center[3 * i + 1]; cz = center[3 * i + 2]; }
        float d0 = cx - mc0, d1 = cy - mcy, d2 = cz - mcz;
        bool act = sqrtf(d0 * d0 + d1 * d1 + d2 * d2) <= 2.0f;
        if (j < 256) e2s[j] = act ? 1.0f : 0.0f;
        if (act) lm2 = fmaxf(lm2, k);
    }
#pragma unroll
    for (int m = 1; m < 64; m <<= 1) lm2 = fmaxf(lm2, __shfl_xor(lm2, m, 64));
    if (lane == 0) wm2[wv] = lm2;
    __syncthreads();
    float m2 = fmaxf(fmaxf(wm2[0], wm2[1]), fmaxf(wm2[2], wm2[3]));

    // ---- pass 3b: e2 weights into LDS + rep (min, order-free) ----
    int lrep = 0x7fffffff;
    for (int j = tid; j < n; j += 256) {
        if (j < 256) {
            bool act = e2s[j] != 0.0f;
            float k = kk[j];
            float e = act ? expf(k - m2) : 0.0f;
            e2s[j] = e;
            if (act && k == m2) lrep = min(lrep, idxs[j]);
        } else {
            int i = lists[base + j];
            float k = keep[i];
            float cx = center[3 * i + 0], cy = center[3 * i + 1], cz = center[3 * i + 2];
            float d0 = cx - mc0, d1 = cy - mcy, d2 = cz - mcz;
            if (sqrtf(d0 * d0 + d1 * d1 + d2 * d2) <= 2.0f && k == m2) lrep = min(lrep, i);
        }
    }
#pragma unroll
    for (int m = 1; m < 64; m <<= 1) lrep = min(lrep, __shfl_xor(lrep, m, 64));
    if (lane == 0) wri[wv] = lrep;
    __syncthreads();                    // also publishes e2s to all waves
    int rep = min(min(wri[0], wri[1]), min(wri[2], wri[3]));

    // ---- pass 4: register-accumulated channel sums, wave-split ----
    {
        float a[17];
#pragma unroll
        for (int c = 0; c < 17; c++) a[c] = 0.f;

        auto e2_glob = [&](int j, int& i) -> float {   // n>256 fallback (never in practice)
            i = lists[base + j];
            float k = keep[i];
            float cx = center[3 * i + 0], cy = center[3 * i + 1], cz = center[3 * i + 2];
            float d0 = cx - mc0, d1 = cy - mcy, d2 = cz - mcz;
            return (sqrtf(d0 * d0 + d1 * d1 + d2 * d2) <= 2.0f) ? expf(k - m2) : 0.0f;
        };

        if (wv == 0) {
            for (int j = lane; j < n; j += 64) {
                float e, cx, cy, cz; int i;
                if (j < 256) { e = e2s[j]; i = idxs[j]; cx = c0s[j]; cy = c1s[j]; cz = c2s[j]; }
                else { e = e2_glob(j, i);
                       cx = center[3 * i + 0]; cy = center[3 * i + 1]; cz = center[3 * i + 2]; }
                if (e != 0.0f) {
                    a[0] += e * cx; a[1] += e * cy; a[2] += e * cz;
                    a[3] += e * offsetp[3 * i + 0]; a[4] += e * offsetp[3 * i + 1]; a[5] += e * offsetp[3 * i + 2];
                    a[6] += e * opacity[i];
                    a[7] += e * scale[3 * i + 0]; a[8] += e * scale[3 * i + 1]; a[9] += e * scale[3 * i + 2];
                    float4 r4 = *(const float4*)(rot + 4 * i);
                    a[10] += e * r4.x; a[11] += e * r4.y; a[12] += e * r4.z; a[13] += e * r4.w;
                    a[14] += e * fd[3 * i + 0]; a[15] += e * fd[3 * i + 1]; a[16] += e * fd[3 * i + 2];
                }
            }
            wreduce_store<17>(a, lane, 0, totl);
        } else if (wv == 1) {
            for (int j = lane; j < n; j += 64) {
                float e; int i;
                if (j < 256) { e = e2s[j]; i = idxs[j]; } else { e = e2_glob(j, i); }
                if (e != 0.0f) {
                    const float4* ip = (const float4*)(inst + 32 * i);
#pragma unroll
                    for (int q = 0; q < 4; q++) {
                        float4 v = ip[q];
                        a[4 * q + 0] += e * v.x; a[4 * q + 1] += e * v.y;
                        a[4 * q + 2] += e * v.z; a[4 * q + 3] += e * v.w;
                    }
                }
            }
            wreduce_store<16>(a, lane, 17, totl);
        } else if (wv == 2) {
            for (int j = lane; j < n; j += 64) {
                float e; int i;
                if (j < 256) { e = e2s[j]; i = idxs[j]; } else { e = e2_glob(j, i); }
                if (e != 0.0f) {
                    const float4* ip = (const float4*)(inst + 32 * i) + 4;
#pragma unroll
                    for (int q = 0; q < 4; q++) {
                        float4 v = ip[q];
                        a[4 * q + 0] += e * v.x; a[4 * q + 1] += e * v.y;
                        a[4 * q + 2] += e * v.z; a[4 * q + 3] += e * v.w;
                    }
                }
            }
            wreduce_store<16>(a, lane, 33, totl);
        } else {
            for (int j = lane; j < n; j += 64) {
                float e; int i;
                if (j < 256) { e = e2s[j]; i = idxs[j]; } else { e = e2_glob(j, i); }
                if (e != 0.0f) {
                    const float4* mp = (const float4*)(motion + 16 * i);
#pragma unroll
                    for (int q = 0; q < 4; q++) {
                        float4 v = mp[q];
                        a[4 * q + 0] += e * v.x; a[4 * q + 1] += e * v.y;
                        a[4 * q + 2] += e * v.z; a[4 * q + 3] += e * v.w;
                    }
                    a[16] += e;     // z2
                }
            }
            wreduce_store<17>(a, lane, 49, totl);
        }
    }
    __syncthreads();

    // ---- finalize: 66 threads write the merged record ----
    if (tid < 66) {
        float z2v = totl[65];
        float inv2 = 1.0f / fmaxf(z2v, 1e-20f);
        float v;
        if (tid < 10) v = totl[tid] * inv2;                          // cen, off, opac, scale
        else if (tid < 14) {                                         // rot (normalized)
            float q0 = totl[10] * inv2, q1 = totl[11] * inv2;
            float q2 = totl[12] * inv2, q3 = totl[13] * inv2;
            float nrm = sqrtf(q0 * q0 + q1 * q1 + q2 * q2 + q3 * q3);
            float rn = 1.0f / fmaxf(nrm, 1e-12f);
            v = (totl[tid] * inv2) * rn;
        }
        else if (tid < 17) v = totl[tid] * inv2;                     // feat_dc
        else if (tid == 17) v = m2;                                  // keep (pre-sfac)
        else v = totl[tid - 1] * inv2;                               // inst, motion
        merged[(long)s * 66 + tid] = v;
    }
    if (tid == 0) {
        mc1g[3 * s + 0] = mc0; mc1g[3 * s + 1] = mcy; mc1g[3 * s + 2] = mcz;
        repg[s] = rep;
    }
}

// ---------------- output: LDS-transposed, fully coalesced ----------------
// 64 elements per block: stage all channels with coalesced reads into
// rec[64][68], patch active elements from merged[], write out as float2.
__global__ __launch_bounds__(256) void k_out(
        const int* __restrict__ gid, const int* __restrict__ cnt,
        const float* __restrict__ keep, const float* __restrict__ center,
        const float* __restrict__ offsetp, const float* __restrict__ opacity,
        const float* __restrict__ scale, const float* __restrict__ rot,
        const float* __restrict__ fd, const float* __restrict__ inst,
        const float* __restrict__ motion,
        const float* __restrict__ mc1g, const int* __restrict__ repg,
        const float* __restrict__ merged,
        float* __restrict__ out) {
    __shared__ float rec[64][68];       // 68 pad: even stride, spreads banks
    __shared__ int   asg[64];
    __shared__ float sf[64];
    int tid = threadIdx.x;
    int e0 = blockIdx.x * 64;

    // Phase A: coalesced staging of all input channels
    if (tid < 192) {
        rec[tid / 3][0  + tid % 3] = center [e0 * 3 + tid];
        rec[tid / 3][3  + tid % 3] = offsetp[e0 * 3 + tid];
        rec[tid / 3][7  + tid % 3] = scale  [e0 * 3 + tid];
        rec[tid / 3][14 + tid % 3] = fd     [e0 * 3 + tid];
    }
    if (tid < 64) {
        rec[tid][6]  = opacity[e0 + tid];
        rec[tid][17] = keep   [e0 + tid];
    }
    rec[tid >> 2][10 + (tid & 3)] = rot[e0 * 4 + tid];
    for (int f = tid; f < 2048; f += 256) rec[f >> 5][18 + (f & 31)] = inst  [e0 * 32 + f];
    for (int f = tid; f < 1024; f += 256) rec[f >> 4][50 + (f & 15)] = motion[e0 * 16 + f];
    __syncthreads();

    // Phase pre: per-element active test (same expressions as k_seg pass 3)
    if (tid < 64) {
        int e = e0 + tid;
        int id = gid[e];
        int sg = -1; float sv = 1.0f;
        if (id >= 0) {
            int seg = (e / kSlab) * kNT + id;
            if (cnt[seg] >= 2) {
                float d0 = rec[tid][0] - mc1g[3 * seg + 0];
                float d1 = rec[tid][1] - mc1g[3 * seg + 1];
                float d2 = rec[tid][2] - mc1g[3 * seg + 2];
                if (sqrtf(d0 * d0 + d1 * d1 + d2 * d2) <= 2.0f) {
                    sg = seg;
                    sv = (e == repg[seg]) ? 1.0f : 0.05f;
                }
            }
        }
        asg[tid] = sg; sf[tid] = sv;
    }
    __syncthreads();

    // Phase B: patch active elements with merged record (L2-hot gathers)
    for (int f = tid; f < 64 * 66; f += 256) {
        int elem = f / 66;
        int sg = asg[elem];
        if (sg >= 0) {
            int c = f - elem * 66;
            float v = merged[(long)sg * 66 + c];
            if (c == 6 || c == 17) v *= sf[elem];
            rec[elem][c] = v;
        }
    }
    __syncthreads();

    // Phase C: coalesced float2 write of 64*66 floats
    float2* o2 = reinterpret_cast<float2*>(out + (size_t)e0 * 66);
    for (int f = tid; f < 64 * 33; f += 256) {
        int elem = f / 33;
        int c2 = f - elem * 33;
        o2[f] = *(const float2*)&rec[elem][c2 * 2];
    }
}

extern "C" void kernel_launch(void* const* d_in, const int* in_sizes, int n_in,
                              void* d_out, int out_size, void* d_ws, size_t ws_size,
                              hipStream_t stream) {
    const float* center = (const float*)d_in[0];
    const float* offsetp = (const float*)d_in[1];
    const float* opacity = (const float*)d_in[2];
    const float* scale = (const float*)d_in[3];
    const float* rot = (const float*)d_in[4];
    const float* fd = (const float*)d_in[5];
    const float* keep = (const float*)d_in[6];
    const float* inst = (const float*)d_in[7];
    const float* motion = (const float*)d_in[8];
    const int* gid = (const int*)d_in[9];
    float* out = (float*)d_out;

    // workspace layout (4-byte units) -- unchanged from previous version
    int* cnt      = (int*)d_ws;                    // [0, 4096)
    int* offs     = (int*)d_ws + 4096;             // [4096, 8192)
    int* cursor   = (int*)d_ws + 8192;             // [8192, 12288)
    float* mc1g   = (float*)d_ws + 12288;          // [12288, 24576)
    // (float*)d_ws + 24576 .. 28672: former m2g slot, now unused
    int* repg     = (int*)d_ws + 28672;            // [28672, 32768)
    float* merged = (float*)d_ws + 32768;          // [32768, 303104)  66*4096
    int* lists    = (int*)d_ws + 303104;           // [303104, 1040384) BN ints

    hipMemsetAsync(cnt, 0, (size_t)kNSeg * 4, stream);

    k_count<<<kBN / kChunk, 1024, 0, stream>>>(gid, cnt);
    k_scan<<<1, 1024, 0, stream>>>(cnt, offs, cursor);
    k_fill<<<kBN / kChunk, 1024, 0, stream>>>(gid, cursor, lists);
    k_seg<<<kNSeg, 256, 0, stream>>>(lists, offs, cnt, keep, center, offsetp, opacity,
                                     scale, rot, fd, inst, motion, mc1g, repg, merged);
    k_out<<<kBN / 64, 256, 0, stream>>>(gid, cnt, keep, center, offsetp, opacity, scale,
                                        rot, fd, inst, motion, mc1g, repg, merged, out);
}